// Round 5
// baseline (365.930 us; speedup 1.0000x reference)
//
#include <hip/hip_runtime.h>

// ComplexMultiHeadAttention: B=2, N=2048, D=1024, H=16, hd=64
// Fast path (ws >= 84MB): [cvt_prepass f32->bf16] -> [qkv_gemm_dma] -> [attn_fwd]
//                         -> [out_gemm_dma] ; obuf aliases xbf (dead after qkv).
// Fallback (small ws): legacy GEMMs + same attn.

#define DIM_   1024
#define HEADS_ 16
#define HD_    64
#define BB_    2
#define NN_    2048
#define MTOT_  (BB_*NN_)      // 4096
#define SCALE_ 0.125f

typedef __bf16 bf16;
typedef __bf16 bf16x8 __attribute__((ext_vector_type(8)));
typedef short  s16x8  __attribute__((ext_vector_type(8)));
typedef float  fx4    __attribute__((ext_vector_type(4)));

__device__ __forceinline__ bf16x8 neg8(bf16x8 v) {
    s16x8 s;
    __builtin_memcpy(&s, &v, sizeof(s));
    s ^= (short)0x8000;
    bf16x8 r;
    __builtin_memcpy(&r, &s, sizeof(r));
    return r;
}

__device__ __forceinline__ void gl_lds16(const void* g, void* l) {
    __builtin_amdgcn_global_load_lds(
        (const __attribute__((address_space(1))) unsigned int*)g,
        (__attribute__((address_space(3))) unsigned int*)l, 16, 0, 0);
}

// ---------------------------------------------------------------------------
// Prepass: f32 -> bf16 for x (8.39M), Wqkv (6.29M), Wout (2.1M). 8192 blocks.
// ---------------------------------------------------------------------------
__global__ __launch_bounds__(256) void cvt_prepass(
    const float* __restrict__ xr, const float* __restrict__ xi,
    const float* __restrict__ wqr, const float* __restrict__ wqi,
    const float* __restrict__ wor, const float* __restrict__ woi,
    bf16* __restrict__ xbf, bf16* __restrict__ wqkv, bf16* __restrict__ wout)
{
    const int bid = blockIdx.x;
    const float* src; bf16* dst; int rel;
    if      (bid < 2048) { src = xr;  dst = xbf;           rel = bid; }
    else if (bid < 4096) { src = xi;  dst = xbf + 4194304; rel = bid - 2048; }
    else if (bid < 5632) { src = wqr; dst = wqkv;          rel = bid - 4096; }
    else if (bid < 7168) { src = wqi; dst = wqkv + 3145728; rel = bid - 5632; }
    else if (bid < 7680) { src = wor; dst = wout;          rel = bid - 7168; }
    else                 { src = woi; dst = wout + 1048576; rel = bid - 7680; }
    size_t base = (size_t)rel * 2048 + (size_t)threadIdx.x * 8;
    fx4 a = *(const fx4*)(src + base);
    fx4 b = *(const fx4*)(src + base + 4);
    bf16x8 o;
#pragma unroll
    for (int j = 0; j < 4; ++j) { o[j] = (bf16)a[j]; o[j+4] = (bf16)b[j]; }
    *(bf16x8*)(dst + base) = o;
}

// ---------------------------------------------------------------------------
// m97-style GEMM core: C[m,c] = A[m,:].B[c,:], A/B bf16 row-major [rows][1024].
// 128x128 tile, BK=64, global_load_lds w16, XOR-swizzled chunks, 2 barriers.
// ---------------------------------------------------------------------------
#define GEMM_CORE(Aptr, Bptr)                                                  \
    __shared__ __align__(16) bf16 As[128*64];                                  \
    __shared__ __align__(16) bf16 Bs[128*64];                                  \
    const int tid  = threadIdx.x;                                              \
    const int w    = tid >> 6, lane = tid & 63;                                \
    const int quad = lane >> 4, lc = lane & 15;                                \
    const int wm   = (w >> 1) * 64, wn = (w & 1) * 64;                         \
    const int rj   = lane >> 3;                                                \
    const int sc   = (lane & 7) ^ rj;                                          \
    const fx4 fzero = {0.f, 0.f, 0.f, 0.f};                                    \
    fx4 acc[4][4];                                                             \
    _Pragma("unroll")                                                          \
    for (int mi = 0; mi < 4; ++mi)                                             \
        _Pragma("unroll")                                                      \
        for (int ni = 0; ni < 4; ++ni) acc[mi][ni] = fzero;                    \
    for (int k0 = 0; k0 < DIM_; k0 += 64) {                                    \
        _Pragma("unroll")                                                      \
        for (int j = 0; j < 4; ++j) {                                          \
            int grp = j*4 + w;                                                 \
            int gr  = grp*8 + rj;                                              \
            gl_lds16(Aptr + (size_t)(m0+gr)*DIM_ + k0 + sc*8, As + grp*512);   \
            gl_lds16(Bptr + (size_t)(n0+gr)*DIM_ + k0 + sc*8, Bs + grp*512);   \
        }                                                                      \
        __syncthreads();                                                       \
        bf16x8 af[2][4], bfr[2][4];                                            \
        _Pragma("unroll")                                                      \
        for (int ks = 0; ks < 2; ++ks) {                                       \
            _Pragma("unroll")                                                  \
            for (int mi = 0; mi < 4; ++mi)                                     \
                af[ks][mi] = *(bf16x8*)&As[(wm+mi*16+lc)*64 + (((ks*4+quad)^(lc&7))*8)]; \
            _Pragma("unroll")                                                  \
            for (int ni = 0; ni < 4; ++ni)                                     \
                bfr[ks][ni] = *(bf16x8*)&Bs[(wn+ni*16+lc)*64 + (((ks*4+quad)^(lc&7))*8)]; \
        }                                                                      \
        _Pragma("unroll")                                                      \
        for (int ks = 0; ks < 2; ++ks)                                         \
            _Pragma("unroll")                                                  \
            for (int mi = 0; mi < 4; ++mi)                                     \
                _Pragma("unroll")                                              \
                for (int ni = 0; ni < 4; ++ni)                                 \
                    acc[mi][ni] = __builtin_amdgcn_mfma_f32_16x16x32_bf16(     \
                        af[ks][mi], bfr[ks][ni], acc[mi][ni], 0, 0, 0);        \
        __syncthreads();                                                       \
    }

__global__ __launch_bounds__(256) void qkv_gemm_dma(
    const bf16* __restrict__ xbf, const bf16* __restrict__ wqkv,
    const float* __restrict__ br, const float* __restrict__ bi,
    bf16* __restrict__ qbuf, bf16* __restrict__ kbuf, bf16* __restrict__ vbuf)
{
    const int z = blockIdx.z;
    const bf16* __restrict__ Ap = xbf  + (size_t)z * 4194304;
    const bf16* __restrict__ Bp = wqkv + (size_t)z * 3145728;
    const float* __restrict__ bias = z ? bi : br;
    const int n0 = blockIdx.x * 128;
    const int m0 = blockIdx.y * 128;

    GEMM_CORE(Ap, Bp)

#pragma unroll
    for (int mi = 0; mi < 4; ++mi)
#pragma unroll
        for (int ni = 0; ni < 4; ++ni)
#pragma unroll
            for (int r = 0; r < 4; ++r) {
                int gm = m0 + wm + mi*16 + quad*4 + r;
                int gc = n0 + wn + ni*16 + lc;
                float val = acc[mi][ni][r] + bias[gc];
                bf16 bv = (bf16)val;
                int which = gc >> 10, h = (gc >> 6) & 15, hd = gc & 63;
                int b = gm >> 11, n = gm & 2047;
                size_t base = (size_t)((z*BB_ + b)*HEADS_ + h);
                if (which == 0)      qbuf[(base*NN_ + n)*HD_ + hd] = bv;
                else if (which == 1) kbuf[(base*NN_ + n)*HD_ + hd] = bv;
                else                 vbuf[(base*HD_ + hd)*NN_ + n] = bv;   // V transposed
            }
}

__global__ __launch_bounds__(256) void out_gemm_dma(
    const bf16* __restrict__ obuf, const bf16* __restrict__ wout,
    const float* __restrict__ br, const float* __restrict__ bi,
    float* __restrict__ out)
{
    const int z = blockIdx.z;
    const bf16* __restrict__ Ap = obuf + (size_t)z * 4194304;
    const bf16* __restrict__ Bp = wout + (size_t)z * 1048576;
    const float* __restrict__ bias = z ? bi : br;
    float* __restrict__ dst = out + (size_t)z * 4194304;
    const int n0 = blockIdx.x * 128;
    const int m0 = blockIdx.y * 128;

    GEMM_CORE(Ap, Bp)

#pragma unroll
    for (int mi = 0; mi < 4; ++mi)
#pragma unroll
        for (int ni = 0; ni < 4; ++ni)
#pragma unroll
            for (int r = 0; r < 4; ++r) {
                int gm = m0 + wm + mi*16 + quad*4 + r;
                int gc = n0 + wn + ni*16 + lc;
                dst[(size_t)gm*DIM_ + gc] = acc[mi][ni][r] + bias[gc];
            }
}

// ---------------------------------------------------------------------------
// Flash attention v3: 1024 blocks x 4 waves; each wave owns 16 Q rows.
//  - 4 blocks/CU resident (LDS 37.9KB, launch_bounds(256,4)) -> 16 waves/CU.
//  - K/V double-buffered 32-key LDS tiles via global_load_lds w16.
//  - V chunk swizzle uses ((r>>1)&3): V row stride is 64B so the bank phase
//    flips every 2 rows; (r&3) left a 4-way conflict (R4: 5.2e6 conflicts).
//  - Ps single-buffered & wave-private (pre-read into regs before barrier).
//  - No online max (scores bounded); l-reduction deferred to epilogue.
// ---------------------------------------------------------------------------
#define KT 32
#define NSTEP (NN_/KT)

__global__ __launch_bounds__(256, 4) void attn_fwd(
    const bf16* __restrict__ qbuf, const bf16* __restrict__ kbuf,
    const bf16* __restrict__ vbuf, bf16* __restrict__ obuf)
{
    const int bid = blockIdx.x;          // 0..1023
    const int xcd = bid & 7;
    const int loc = bid >> 3;            // 0..127
    const int hb  = xcd*4 + (loc >> 5);  // 0..31  (4 (b,h) streams per XCD)
    const int blk = loc & 31;            // 0..31
    const int b = hb >> 4, h = hb & 15;

    const int tid  = threadIdx.x;
    const int w    = tid >> 6, lane = tid & 63;
    const int quad = lane >> 4, lc = lane & 15;
    const int q0   = blk*64 + w*16;      // this wave's 16 Q rows

    __shared__ __align__(16) bf16 KV[2*8192];     // [buf][Kr|Ki|Vr|Vi] 4KB each
    __shared__ __align__(16) bf16 Ps[4*16*40];    // wave-private P tiles
    bf16* psw = Ps + w*(16*40);

    const size_t hR = (size_t)(b)*HEADS_ + h;
    const size_t hI = (size_t)(BB_ + b)*HEADS_ + h;
    const bf16* qrg = qbuf + hR*NN_*HD_;
    const bf16* qig = qbuf + hI*NN_*HD_;
    const char* krg = (const char*)(kbuf + hR*NN_*HD_);
    const char* kig = (const char*)(kbuf + hI*NN_*HD_);
    const char* vrg = (const char*)(vbuf + hR*HD_*NN_);
    const char* vig = (const char*)(vbuf + hI*HD_*NN_);

    // ---- Q fragments (single band) ----
    const bf16* pr = qrg + (size_t)(q0 + lc)*HD_ + quad*8;
    const bf16* pi = qig + (size_t)(q0 + lc)*HD_ + quad*8;
    bf16x8 qr0 = *(const bf16x8*)(pr);
    bf16x8 qr1 = *(const bf16x8*)(pr + 32);
    bf16x8 qi0 = *(const bf16x8*)(pi);
    bf16x8 qi1 = *(const bf16x8*)(pi + 32);
    bf16x8 nqr0 = neg8(qr0), nqr1 = neg8(qr1);

    // ---- staging: wave w DMAs array w (0=Kr,1=Ki,2=Vr,3=Vi) ----
    // K tile: 32 rows x 128B (8 chunks), slot = c ^ (r&7)
    // V tile: 64 rows x  64B (4 chunks), slot = c ^ ((r>>1)&3)
    const char* stg_base;
    size_t lane_off, step_mul, j_mul;
    if (w < 2) {
        stg_base = w ? kig : krg;
        lane_off = (size_t)(lane >> 3)*128 + (size_t)((lane & 7) ^ (lane >> 3))*16;
        step_mul = (size_t)KT * 128;
        j_mul    = 1024;
    } else {
        stg_base = (w == 3) ? vig : vrg;
        lane_off = (size_t)(lane >> 2)*4096 + (size_t)((lane & 3) ^ ((lane >> 3) & 3))*16;
        step_mul = (size_t)KT * 2;
        j_mul    = 65536;
    }
    bf16* lds_arr = KV + w*2048;

    const fx4 fzero = {0.f, 0.f, 0.f, 0.f};
    fx4 O[2][4];                // [ri][vb]
    float l_[4];
#pragma unroll
    for (int r = 0; r < 4; ++r) l_[r] = 0.f;
#pragma unroll
    for (int ri = 0; ri < 2; ++ri)
#pragma unroll
        for (int vb = 0; vb < 4; ++vb) O[ri][vb] = fzero;
    bf16x8 pf;                  // P A-frag (prev step)
    bf16x8 vf[2][4];            // V B-frags (prev step)

    const float CEXP = SCALE_ * 1.44269504f;   // exp2(CEXP * mag)

    // prologue: stage tile 0
    {
        const char* g = stg_base + lane_off;
#pragma unroll
        for (int j = 0; j < 4; ++j)
            gl_lds16(g + j*j_mul, lds_arr + j*512);
    }
    __syncthreads();

    for (int s = 0; s < NSTEP; ++s) {
        const int buf = s & 1;
        bf16* kvb = KV + buf*8192;

        // ---- DMA tile s+1 into other buffer ----
        if (s < NSTEP-1) {
            const char* g = stg_base + (size_t)(s+1)*step_mul + lane_off;
            bf16* l = lds_arr + (buf ^ 1)*8192;
#pragma unroll
            for (int j = 0; j < 4; ++j)
                gl_lds16(g + j*j_mul, l + j*512);
        }

        // ---- PV for step s-1 ----
        if (s > 0) {
#pragma unroll
            for (int ri = 0; ri < 2; ++ri)
#pragma unroll
                for (int vb = 0; vb < 4; ++vb)
                    O[ri][vb] = __builtin_amdgcn_mfma_f32_16x16x32_bf16(
                        pf, vf[ri][vb], O[ri][vb], 0, 0, 0);
        }

        // ---- S(s): complex scores + exp ----
#pragma unroll
        for (int kb = 0; kb < 2; ++kb) {
            int r = kb*16 + lc;
            int c0 = quad ^ (r & 7);
            int c1 = (4 + quad) ^ (r & 7);
            bf16x8 kr0f = *(bf16x8*)&kvb[0*2048 + r*64 + c0*8];
            bf16x8 kr1f = *(bf16x8*)&kvb[0*2048 + r*64 + c1*8];
            bf16x8 ki0f = *(bf16x8*)&kvb[1*2048 + r*64 + c0*8];
            bf16x8 ki1f = *(bf16x8*)&kvb[1*2048 + r*64 + c1*8];
            fx4 sr = fzero, si = fzero;
            sr = __builtin_amdgcn_mfma_f32_16x16x32_bf16(qr0,  kr0f, sr, 0,0,0);
            sr = __builtin_amdgcn_mfma_f32_16x16x32_bf16(qr1,  kr1f, sr, 0,0,0);
            sr = __builtin_amdgcn_mfma_f32_16x16x32_bf16(qi0,  ki0f, sr, 0,0,0);
            sr = __builtin_amdgcn_mfma_f32_16x16x32_bf16(qi1,  ki1f, sr, 0,0,0);
            si = __builtin_amdgcn_mfma_f32_16x16x32_bf16(qi0,  kr0f, si, 0,0,0);
            si = __builtin_amdgcn_mfma_f32_16x16x32_bf16(qi1,  kr1f, si, 0,0,0);
            si = __builtin_amdgcn_mfma_f32_16x16x32_bf16(nqr0, ki0f, si, 0,0,0);
            si = __builtin_amdgcn_mfma_f32_16x16x32_bf16(nqr1, ki1f, si, 0,0,0);
#pragma unroll
            for (int r4 = 0; r4 < 4; ++r4) {
                float s2 = sr[r4]*sr[r4] + si[r4]*si[r4];
                float mg = __builtin_amdgcn_sqrtf(s2);
                float pv = __builtin_amdgcn_exp2f(mg * CEXP);
                l_[r4] += pv;
                psw[(quad*4 + r4)*40 + kb*16 + lc] = (bf16)pv;
            }
        }

        // ---- pre-read next-iteration operands (before barrier) ----
        pf = *(bf16x8*)&psw[lc*40 + quad*8];
#pragma unroll
        for (int ri = 0; ri < 2; ++ri)
#pragma unroll
            for (int vb = 0; vb < 4; ++vb) {
                int r = vb*16 + lc;
                int c = quad ^ ((r >> 1) & 3);
                vf[ri][vb] = *(bf16x8*)&kvb[(2+ri)*2048 + r*32 + c*8];
            }

        __syncthreads();
    }

    // ---- final PV ----
#pragma unroll
    for (int ri = 0; ri < 2; ++ri)
#pragma unroll
        for (int vb = 0; vb < 4; ++vb)
            O[ri][vb] = __builtin_amdgcn_mfma_f32_16x16x32_bf16(
                pf, vf[ri][vb], O[ri][vb], 0, 0, 0);

    // ---- row-sum reduce over 16 lc lanes, normalize, store ----
#pragma unroll
    for (int off = 1; off < 16; off <<= 1)
#pragma unroll
        for (int r = 0; r < 4; ++r)
            l_[r] += __shfl_xor(l_[r], off);
    float inv[4];
#pragma unroll
    for (int r = 0; r < 4; ++r) inv[r] = 1.f / l_[r];

    bf16* obr = obuf + ((size_t)(b)*NN_)*DIM_;
    bf16* obi = obuf + ((size_t)(BB_ + b)*NN_)*DIM_;
#pragma unroll
    for (int vb = 0; vb < 4; ++vb)
#pragma unroll
        for (int r = 0; r < 4; ++r) {
            int gn = q0 + quad*4 + r;
            int gc = h*HD_ + vb*16 + lc;
            obr[(size_t)gn*DIM_ + gc] = (bf16)(O[0][vb][r] * inv[r]);
            obi[(size_t)gn*DIM_ + gc] = (bf16)(O[1][vb][r] * inv[r]);
        }
}

// ---------------------------------------------------------------------------
// Legacy (round-3) GEMMs — fallback when ws_size < 84 MB.
// ---------------------------------------------------------------------------
__global__ __launch_bounds__(256) void qkv_gemm_legacy(
    const float* __restrict__ xr, const float* __restrict__ xi,
    const float* __restrict__ Wr, const float* __restrict__ Wi,
    const float* __restrict__ br, const float* __restrict__ bi,
    bf16* __restrict__ qbuf, bf16* __restrict__ kbuf, bf16* __restrict__ vbuf)
{
    const int z = blockIdx.z;
    const float* __restrict__ A    = z ? xi : xr;
    const float* __restrict__ W    = z ? Wi : Wr;
    const float* __restrict__ bias = z ? bi : br;
    const int n0 = blockIdx.x * 128;
    const int m0 = blockIdx.y * 128;

    __shared__ bf16 As[128*40];
    __shared__ bf16 Bs[128*40];

    const int tid  = threadIdx.x;
    const int w    = tid >> 6, lane = tid & 63;
    const int quad = lane >> 4, lc = lane & 15;
    const int wm   = (w >> 1) * 64, wn = (w & 1) * 64;

    const fx4 fzero = {0.f, 0.f, 0.f, 0.f};
    fx4 acc[4][4];
#pragma unroll
    for (int mi = 0; mi < 4; ++mi)
#pragma unroll
        for (int ni = 0; ni < 4; ++ni) acc[mi][ni] = fzero;

    for (int k0 = 0; k0 < DIM_; k0 += 32) {
#pragma unroll
        for (int it = 0; it < 2; ++it) {
            int flat = it*2048 + tid*8;
            int row = flat >> 5, col = flat & 31;
            const float* pa = A + (size_t)(m0+row)*DIM_ + k0 + col;
            const float* pb = W + (size_t)(n0+row)*DIM_ + k0 + col;
            fx4 a0 = *(const fx4*)pa, a1 = *(const fx4*)(pa+4);
            fx4 b0 = *(const fx4*)pb, b1 = *(const fx4*)(pb+4);
            bf16x8 av, bv;
#pragma unroll
            for (int j = 0; j < 4; ++j) {
                av[j] = (bf16)a0[j]; av[j+4] = (bf16)a1[j];
                bv[j] = (bf16)b0[j]; bv[j+4] = (bf16)b1[j];
            }
            *(bf16x8*)&As[row*40 + col] = av;
            *(bf16x8*)&Bs[row*40 + col] = bv;
        }
        __syncthreads();

        bf16x8 af[4], bfr[4];
#pragma unroll
        for (int mi = 0; mi < 4; ++mi) af[mi]  = *(bf16x8*)&As[(wm + mi*16 + lc)*40 + quad*8];
#pragma unroll
        for (int ni = 0; ni < 4; ++ni) bfr[ni] = *(bf16x8*)&Bs[(wn + ni*16 + lc)*40 + quad*8];
#pragma unroll
        for (int mi = 0; mi < 4; ++mi)
#pragma unroll
            for (int ni = 0; ni < 4; ++ni)
                acc[mi][ni] = __builtin_amdgcn_mfma_f32_16x16x32_bf16(af[mi], bfr[ni], acc[mi][ni], 0, 0, 0);
        __syncthreads();
    }

#pragma unroll
    for (int mi = 0; mi < 4; ++mi)
#pragma unroll
        for (int ni = 0; ni < 4; ++ni)
#pragma unroll
            for (int r = 0; r < 4; ++r) {
                int gm = m0 + wm + mi*16 + quad*4 + r;
                int gc = n0 + wn + ni*16 + lc;
                float val = acc[mi][ni][r] + bias[gc];
                bf16 bv = (bf16)val;
                int which = gc >> 10, h = (gc >> 6) & 15, hd = gc & 63;
                int b = gm >> 11, n = gm & 2047;
                size_t base = (size_t)((z*BB_ + b)*HEADS_ + h);
                if (which == 0)      qbuf[(base*NN_ + n)*HD_ + hd] = bv;
                else if (which == 1) kbuf[(base*NN_ + n)*HD_ + hd] = bv;
                else                 vbuf[(base*HD_ + hd)*NN_ + n] = bv;
            }
}

__global__ __launch_bounds__(256) void out_gemm_legacy(
    const bf16* __restrict__ obuf,
    const float* __restrict__ Wr, const float* __restrict__ Wi,
    const float* __restrict__ br, const float* __restrict__ bi,
    float* __restrict__ out)
{
    const int z = blockIdx.z;
    const bf16*  __restrict__ A    = obuf + (size_t)z * MTOT_ * DIM_;
    const float* __restrict__ W    = z ? Wi : Wr;
    const float* __restrict__ bias = z ? bi : br;
    float* __restrict__ dst        = out + (size_t)z * MTOT_ * DIM_;
    const int n0 = blockIdx.x * 128;
    const int m0 = blockIdx.y * 128;

    __shared__ bf16 As[128*40];
    __shared__ bf16 Bs[128*40];

    const int tid  = threadIdx.x;
    const int w    = tid >> 6, lane = tid & 63;
    const int quad = lane >> 4, lc = lane & 15;
    const int wm   = (w >> 1) * 64, wn = (w & 1) * 64;

    const fx4 fzero = {0.f, 0.f, 0.f, 0.f};
    fx4 acc[4][4];
#pragma unroll
    for (int mi = 0; mi < 4; ++mi)
#pragma unroll
        for (int ni = 0; ni < 4; ++ni) acc[mi][ni] = fzero;

    for (int k0 = 0; k0 < DIM_; k0 += 32) {
#pragma unroll
        for (int it = 0; it < 2; ++it) {
            int flat = it*2048 + tid*8;
            int row = flat >> 5, col = flat & 31;
            *(bf16x8*)&As[row*40 + col] = *(const bf16x8*)(A + (size_t)(m0+row)*DIM_ + k0 + col);
            const float* pb = W + (size_t)(n0+row)*DIM_ + k0 + col;
            fx4 b0 = *(const fx4*)pb, b1 = *(const fx4*)(pb+4);
            bf16x8 bv;
#pragma unroll
            for (int j = 0; j < 4; ++j) { bv[j] = (bf16)b0[j]; bv[j+4] = (bf16)b1[j]; }
            *(bf16x8*)&Bs[row*40 + col] = bv;
        }
        __syncthreads();

        bf16x8 af[4], bfr[4];
#pragma unroll
        for (int mi = 0; mi < 4; ++mi) af[mi]  = *(bf16x8*)&As[(wm + mi*16 + lc)*40 + quad*8];
#pragma unroll
        for (int ni = 0; ni < 4; ++ni) bfr[ni] = *(bf16x8*)&Bs[(wn + ni*16 + lc)*40 + quad*8];
#pragma unroll
        for (int mi = 0; mi < 4; ++mi)
#pragma unroll
            for (int ni = 0; ni < 4; ++ni)
                acc[mi][ni] = __builtin_amdgcn_mfma_f32_16x16x32_bf16(af[mi], bfr[ni], acc[mi][ni], 0, 0, 0);
        __syncthreads();
    }

#pragma unroll
    for (int mi = 0; mi < 4; ++mi)
#pragma unroll
        for (int ni = 0; ni < 4; ++ni)
#pragma unroll
            for (int r = 0; r < 4; ++r) {
                int gm = m0 + wm + mi*16 + quad*4 + r;
                int gc = n0 + wn + ni*16 + lc;
                dst[(size_t)gm*DIM_ + gc] = acc[mi][ni][r] + bias[gc];
            }
}

// ---------------------------------------------------------------------------
extern "C" void kernel_launch(void* const* d_in, const int* in_sizes, int n_in,
                              void* d_out, int out_size, void* d_ws, size_t ws_size,
                              hipStream_t stream) {
    const float* xr  = (const float*)d_in[0];
    const float* xi  = (const float*)d_in[1];
    const float* Wqr = (const float*)d_in[2];
    const float* bqr = (const float*)d_in[3];
    const float* Wqi = (const float*)d_in[4];
    const float* bqi = (const float*)d_in[5];
    const float* Wor = (const float*)d_in[6];
    const float* bor = (const float*)d_in[7];
    const float* Woi = (const float*)d_in[8];
    const float* boi = (const float*)d_in[9];
    float* out = (float*)d_out;

    bf16* ws = (bf16*)d_ws;
    const size_t NEED = 83886080ull;

    if (ws_size >= NEED) {
        bf16* xbf  = ws;               // reused as obuf after qkv
        bf16* wqkv = ws + 8388608;
        bf16* wout = ws + 14680064;
        bf16* qb   = ws + 16777216;
        bf16* kb   = ws + 25165824;
        bf16* vb   = ws + 33554432;
        bf16* obuf = xbf;

        cvt_prepass<<<dim3(8192), 256, 0, stream>>>(xr, xi, Wqr, Wqi, Wor, Woi,
                                                    xbf, wqkv, wout);
        qkv_gemm_dma<<<dim3(24, 32, 2), 256, 0, stream>>>(xbf, wqkv, bqr, bqi,
                                                          qb, kb, vb);
        attn_fwd<<<dim3(1024), 256, 0, stream>>>(qb, kb, vb, obuf);
        out_gemm_dma<<<dim3(8, 32, 2), 256, 0, stream>>>(obuf, wout, bor, boi, out);
    } else {
        const size_t per = (size_t)2 * BB_ * HEADS_ * NN_ * HD_;
        bf16* qb   = ws;
        bf16* kb   = ws + per;
        bf16* vb   = ws + 2*per;
        bf16* obuf = ws + 3*per;
        qkv_gemm_legacy<<<dim3(24, 32, 2), 256, 0, stream>>>(xr, xi, Wqr, Wqi,
                                                             bqr, bqi, qb, kb, vb);
        attn_fwd<<<dim3(1024), 256, 0, stream>>>(qb, kb, vb, obuf);
        out_gemm_legacy<<<dim3(8, 32, 2), 256, 0, stream>>>(obuf, Wor, Woi,
                                                            bor, boi, out);
    }
}

// Round 6
// 346.960 us; speedup vs baseline: 1.0547x; 1.0547x over previous
//
#include <hip/hip_runtime.h>

// ComplexMultiHeadAttention: B=2, N=2048, D=1024, H=16, hd=64
// Fast path (ws >= 84MB): [cvt_prepass f32->bf16] -> [qkv_gemm_dma] -> [attn_fwd]
//                         -> [out_gemm_dma] ; obuf aliases xbf (dead after qkv).
// Fallback (small ws): legacy GEMMs + same attn.

#define DIM_   1024
#define HEADS_ 16
#define HD_    64
#define BB_    2
#define NN_    2048
#define MTOT_  (BB_*NN_)      // 4096
#define SCALE_ 0.125f

typedef __bf16 bf16;
typedef __bf16 bf16x8 __attribute__((ext_vector_type(8)));
typedef short  s16x8  __attribute__((ext_vector_type(8)));
typedef float  fx4    __attribute__((ext_vector_type(4)));

__device__ __forceinline__ bf16x8 neg8(bf16x8 v) {
    s16x8 s;
    __builtin_memcpy(&s, &v, sizeof(s));
    s ^= (short)0x8000;
    bf16x8 r;
    __builtin_memcpy(&r, &s, sizeof(r));
    return r;
}

__device__ __forceinline__ void gl_lds16(const void* g, void* l) {
    __builtin_amdgcn_global_load_lds(
        (const __attribute__((address_space(1))) unsigned int*)g,
        (__attribute__((address_space(3))) unsigned int*)l, 16, 0, 0);
}

// CK-style pipeline barrier: drain all but the newest 2 of this wave's DMAs,
// then block-barrier. NO vmcnt(0): tile s+2's DMA stays in flight across it.
#define PIPE_SYNC() asm volatile("s_waitcnt vmcnt(2)\n\ts_barrier" ::: "memory")

// ---------------------------------------------------------------------------
// Prepass: f32 -> bf16 for x (8.39M), Wqkv (6.29M), Wout (2.1M). 8192 blocks.
// ---------------------------------------------------------------------------
__global__ __launch_bounds__(256) void cvt_prepass(
    const float* __restrict__ xr, const float* __restrict__ xi,
    const float* __restrict__ wqr, const float* __restrict__ wqi,
    const float* __restrict__ wor, const float* __restrict__ woi,
    bf16* __restrict__ xbf, bf16* __restrict__ wqkv, bf16* __restrict__ wout)
{
    const int bid = blockIdx.x;
    const float* src; bf16* dst; int rel;
    if      (bid < 2048) { src = xr;  dst = xbf;           rel = bid; }
    else if (bid < 4096) { src = xi;  dst = xbf + 4194304; rel = bid - 2048; }
    else if (bid < 5632) { src = wqr; dst = wqkv;          rel = bid - 4096; }
    else if (bid < 7168) { src = wqi; dst = wqkv + 3145728; rel = bid - 5632; }
    else if (bid < 7680) { src = wor; dst = wout;          rel = bid - 7168; }
    else                 { src = woi; dst = wout + 1048576; rel = bid - 7680; }
    size_t base = (size_t)rel * 2048 + (size_t)threadIdx.x * 8;
    fx4 a = *(const fx4*)(src + base);
    fx4 b = *(const fx4*)(src + base + 4);
    bf16x8 o;
#pragma unroll
    for (int j = 0; j < 4; ++j) { o[j] = (bf16)a[j]; o[j+4] = (bf16)b[j]; }
    *(bf16x8*)(dst + base) = o;
}

// ---------------------------------------------------------------------------
// m97-style GEMM core: C[m,c] = A[m,:].B[c,:], A/B bf16 row-major [rows][1024].
// 128x128 tile, BK=64, global_load_lds w16, XOR-swizzled chunks, 2 barriers.
// ---------------------------------------------------------------------------
#define GEMM_CORE(Aptr, Bptr)                                                  \
    __shared__ __align__(16) bf16 As[128*64];                                  \
    __shared__ __align__(16) bf16 Bs[128*64];                                  \
    const int tid  = threadIdx.x;                                              \
    const int w    = tid >> 6, lane = tid & 63;                                \
    const int quad = lane >> 4, lc = lane & 15;                                \
    const int wm   = (w >> 1) * 64, wn = (w & 1) * 64;                         \
    const int rj   = lane >> 3;                                                \
    const int sc   = (lane & 7) ^ rj;                                          \
    const fx4 fzero = {0.f, 0.f, 0.f, 0.f};                                    \
    fx4 acc[4][4];                                                             \
    _Pragma("unroll")                                                          \
    for (int mi = 0; mi < 4; ++mi)                                             \
        _Pragma("unroll")                                                      \
        for (int ni = 0; ni < 4; ++ni) acc[mi][ni] = fzero;                    \
    for (int k0 = 0; k0 < DIM_; k0 += 64) {                                    \
        _Pragma("unroll")                                                      \
        for (int j = 0; j < 4; ++j) {                                          \
            int grp = j*4 + w;                                                 \
            int gr  = grp*8 + rj;                                              \
            gl_lds16(Aptr + (size_t)(m0+gr)*DIM_ + k0 + sc*8, As + grp*512);   \
            gl_lds16(Bptr + (size_t)(n0+gr)*DIM_ + k0 + sc*8, Bs + grp*512);   \
        }                                                                      \
        __syncthreads();                                                       \
        bf16x8 af[2][4], bfr[2][4];                                            \
        _Pragma("unroll")                                                      \
        for (int ks = 0; ks < 2; ++ks) {                                       \
            _Pragma("unroll")                                                  \
            for (int mi = 0; mi < 4; ++mi)                                     \
                af[ks][mi] = *(bf16x8*)&As[(wm+mi*16+lc)*64 + (((ks*4+quad)^(lc&7))*8)]; \
            _Pragma("unroll")                                                  \
            for (int ni = 0; ni < 4; ++ni)                                     \
                bfr[ks][ni] = *(bf16x8*)&Bs[(wn+ni*16+lc)*64 + (((ks*4+quad)^(lc&7))*8)]; \
        }                                                                      \
        _Pragma("unroll")                                                      \
        for (int ks = 0; ks < 2; ++ks)                                         \
            _Pragma("unroll")                                                  \
            for (int mi = 0; mi < 4; ++mi)                                     \
                _Pragma("unroll")                                              \
                for (int ni = 0; ni < 4; ++ni)                                 \
                    acc[mi][ni] = __builtin_amdgcn_mfma_f32_16x16x32_bf16(     \
                        af[ks][mi], bfr[ks][ni], acc[mi][ni], 0, 0, 0);        \
        __syncthreads();                                                       \
    }

__global__ __launch_bounds__(256) void qkv_gemm_dma(
    const bf16* __restrict__ xbf, const bf16* __restrict__ wqkv,
    const float* __restrict__ br, const float* __restrict__ bi,
    bf16* __restrict__ qbuf, bf16* __restrict__ kbuf, bf16* __restrict__ vbuf)
{
    const int z = blockIdx.z;
    const bf16* __restrict__ Ap = xbf  + (size_t)z * 4194304;
    const bf16* __restrict__ Bp = wqkv + (size_t)z * 3145728;
    const float* __restrict__ bias = z ? bi : br;
    const int n0 = blockIdx.x * 128;
    const int m0 = blockIdx.y * 128;

    GEMM_CORE(Ap, Bp)

#pragma unroll
    for (int mi = 0; mi < 4; ++mi)
#pragma unroll
        for (int ni = 0; ni < 4; ++ni)
#pragma unroll
            for (int r = 0; r < 4; ++r) {
                int gm = m0 + wm + mi*16 + quad*4 + r;
                int gc = n0 + wn + ni*16 + lc;
                float val = acc[mi][ni][r] + bias[gc];
                bf16 bv = (bf16)val;
                int which = gc >> 10, h = (gc >> 6) & 15, hd = gc & 63;
                int b = gm >> 11, n = gm & 2047;
                size_t base = (size_t)((z*BB_ + b)*HEADS_ + h);
                if (which == 0)      qbuf[(base*NN_ + n)*HD_ + hd] = bv;
                else if (which == 1) kbuf[(base*NN_ + n)*HD_ + hd] = bv;
                else                 vbuf[(base*HD_ + hd)*NN_ + n] = bv;   // V transposed
            }
}

__global__ __launch_bounds__(256) void out_gemm_dma(
    const bf16* __restrict__ obuf, const bf16* __restrict__ wout,
    const float* __restrict__ br, const float* __restrict__ bi,
    float* __restrict__ out)
{
    const int z = blockIdx.z;
    const bf16* __restrict__ Ap = obuf + (size_t)z * 4194304;
    const bf16* __restrict__ Bp = wout + (size_t)z * 1048576;
    const float* __restrict__ bias = z ? bi : br;
    float* __restrict__ dst = out + (size_t)z * 4194304;
    const int n0 = blockIdx.x * 128;
    const int m0 = blockIdx.y * 128;

    GEMM_CORE(Ap, Bp)

#pragma unroll
    for (int mi = 0; mi < 4; ++mi)
#pragma unroll
        for (int ni = 0; ni < 4; ++ni)
#pragma unroll
            for (int r = 0; r < 4; ++r) {
                int gm = m0 + wm + mi*16 + quad*4 + r;
                int gc = n0 + wn + ni*16 + lc;
                dst[(size_t)gm*DIM_ + gc] = acc[mi][ni][r] + bias[gc];
            }
}

// ---------------------------------------------------------------------------
// Flash attention v4: 512 blocks x 8 waves; each wave owns 16 Q rows.
//  - Triple-buffered 32-key K/V tiles, distance-2 prefetch via global_load_lds.
//  - Cross-wave staging (wave w stages array w>>1, half w&1; 2 DMAs/wave/step)
//    => per-wave s_waitcnt vmcnt(2) before s_barrier drains tile s+1 (issued a
//    full step earlier) while tile s+2 stays in flight. NO vmcnt(0) drain —
//    that drain was the R5 stall (syncthreads semantics).
//  - LDS 58KB -> 2 blocks/CU = 16 waves/CU, fully resident (512 blocks).
//  - No online max (scores bounded); l-reduction deferred to epilogue.
// ---------------------------------------------------------------------------
#define KT 32
#define NSTEP (NN_/KT)

__global__ __launch_bounds__(512, 4) void attn_fwd(
    const bf16* __restrict__ qbuf, const bf16* __restrict__ kbuf,
    const bf16* __restrict__ vbuf, bf16* __restrict__ obuf)
{
    const int bid = blockIdx.x;          // 0..511
    const int xcd = bid & 7;
    const int loc = bid >> 3;            // 0..63
    const int hb  = xcd*4 + (loc >> 4);  // 0..31  (4 (b,h) streams per XCD)
    const int blk = loc & 15;            // 0..15
    const int b = hb >> 4, h = hb & 15;

    const int tid  = threadIdx.x;
    const int w    = tid >> 6, lane = tid & 63;   // w: 0..7
    const int quad = lane >> 4, lc = lane & 15;
    const int q0   = blk*128 + w*16;     // this wave's 16 Q rows

    __shared__ __align__(16) bf16 KV[3*8192];     // 3 bufs x [Kr|Ki|Vr|Vi] 4KB each
    __shared__ __align__(16) bf16 Ps[8*16*40];    // wave-private P tiles
    bf16* psw = Ps + w*640;

    const size_t hR = (size_t)(b)*HEADS_ + h;
    const size_t hI = (size_t)(BB_ + b)*HEADS_ + h;
    const bf16* qrg = qbuf + hR*NN_*HD_;
    const bf16* qig = qbuf + hI*NN_*HD_;
    const char* krg = (const char*)(kbuf + hR*NN_*HD_);
    const char* kig = (const char*)(kbuf + hI*NN_*HD_);
    const char* vrg = (const char*)(vbuf + hR*HD_*NN_);
    const char* vig = (const char*)(vbuf + hI*HD_*NN_);

    // ---- Q fragments ----
    const bf16* pr = qrg + (size_t)(q0 + lc)*HD_ + quad*8;
    const bf16* pi = qig + (size_t)(q0 + lc)*HD_ + quad*8;
    bf16x8 qr0 = *(const bf16x8*)(pr);
    bf16x8 qr1 = *(const bf16x8*)(pr + 32);
    bf16x8 qi0 = *(const bf16x8*)(pi);
    bf16x8 qi1 = *(const bf16x8*)(pi + 32);
    bf16x8 nqr0 = neg8(qr0), nqr1 = neg8(qr1);

    // ---- staging: wave w -> array w>>1 (0=Kr,1=Ki,2=Vr,3=Vi), half w&1 ----
    // K tile: 32 rows x 128B (8 chunks), LDS slot s of row r holds chunk s^(r&7)
    // V tile: 64 rows x  64B (4 chunks), slot s of row r holds chunk s^((r>>1)&3)
    const int arr = w >> 1, half = w & 1;
    const char* stg_base = (arr == 0) ? krg : (arr == 1) ? kig
                         : (arr == 2) ? vrg : vig;
    size_t lane_off, step_mul, j_mul;
    if (arr < 2) {
        lane_off = (size_t)(lane >> 3)*128 + (size_t)((lane & 7) ^ (lane >> 3))*16;
        step_mul = 4096;  j_mul = 1024;
    } else {
        lane_off = (size_t)(lane >> 2)*4096 + (size_t)((lane & 3) ^ ((lane >> 3) & 3))*16;
        step_mul = 64;    j_mul = 65536;
    }
    const char* stg0 = stg_base + (size_t)half*2*j_mul + lane_off;
    const int lds_base = arr*2048 + half*1024;    // elems within buffer

    // ---- hoisted LDS fragment offsets (elems) ----
    int koff[2][2], voff[4];
#pragma unroll
    for (int kb = 0; kb < 2; ++kb)
#pragma unroll
        for (int hf = 0; hf < 2; ++hf) {
            int r = kb*16 + lc;
            koff[kb][hf] = r*64 + (((hf*4 + quad) ^ (r & 7))*8);
        }
#pragma unroll
    for (int vb = 0; vb < 4; ++vb) {
        int r = vb*16 + lc;
        voff[vb] = r*32 + ((quad ^ ((r >> 1) & 3))*8);
    }

    // ---- accumulators / pipeline regs ----
    const fx4 fzero = {0.f, 0.f, 0.f, 0.f};
    fx4 O[2][4];
    float l_[4];
#pragma unroll
    for (int r = 0; r < 4; ++r) l_[r] = 0.f;
#pragma unroll
    for (int ri = 0; ri < 2; ++ri)
#pragma unroll
        for (int vb = 0; vb < 4; ++vb) O[ri][vb] = fzero;
    bf16x8 pf;
    bf16x8 vf[2][4];

    const float CEXP = SCALE_ * 1.44269504f;

    // ---- prologue: stage tiles 0 and 1 ----
    {
        bf16* l = KV + lds_base;
        gl_lds16(stg0,          l);
        gl_lds16(stg0 + j_mul,  l + 512);
        l = KV + 8192 + lds_base;
        gl_lds16(stg0 + step_mul,         l);
        gl_lds16(stg0 + step_mul + j_mul, l + 512);
    }
    PIPE_SYNC();   // drains tile 0 (vmcnt(2) leaves tile 1 in flight)

    int b0 = 0, b1 = 8192, b2 = 16384;
    for (int s = 0; s < NSTEP; ++s) {
        // ---- DMA tile s+2 into buffer b2 (freed at barrier end of s-1) ----
        if (s < NSTEP-2) {
            const char* g = stg0 + (size_t)(s+2)*step_mul;
            bf16* l = KV + b2 + lds_base;
            gl_lds16(g,         l);
            gl_lds16(g + j_mul, l + 512);
        }

        // ---- PV for step s-1 (frags in regs, overlaps everything) ----
        if (s > 0) {
#pragma unroll
            for (int ri = 0; ri < 2; ++ri)
#pragma unroll
                for (int vb = 0; vb < 4; ++vb)
                    O[ri][vb] = __builtin_amdgcn_mfma_f32_16x16x32_bf16(
                        pf, vf[ri][vb], O[ri][vb], 0, 0, 0);
        }

        // ---- K fragments from LDS buffer b0 ----
        bf16x8 kr_[2][2], ki_[2][2];
#pragma unroll
        for (int kb = 0; kb < 2; ++kb)
#pragma unroll
            for (int hf = 0; hf < 2; ++hf) {
                kr_[kb][hf] = *(bf16x8*)&KV[b0 + koff[kb][hf]];
                ki_[kb][hf] = *(bf16x8*)&KV[b0 + 2048 + koff[kb][hf]];
            }

        // ---- S(s): complex scores + exp ----
#pragma unroll
        for (int kb = 0; kb < 2; ++kb) {
            fx4 sr = fzero, si = fzero;
            sr = __builtin_amdgcn_mfma_f32_16x16x32_bf16(qr0,  kr_[kb][0], sr, 0,0,0);
            sr = __builtin_amdgcn_mfma_f32_16x16x32_bf16(qr1,  kr_[kb][1], sr, 0,0,0);
            sr = __builtin_amdgcn_mfma_f32_16x16x32_bf16(qi0,  ki_[kb][0], sr, 0,0,0);
            sr = __builtin_amdgcn_mfma_f32_16x16x32_bf16(qi1,  ki_[kb][1], sr, 0,0,0);
            si = __builtin_amdgcn_mfma_f32_16x16x32_bf16(qi0,  kr_[kb][0], si, 0,0,0);
            si = __builtin_amdgcn_mfma_f32_16x16x32_bf16(qi1,  kr_[kb][1], si, 0,0,0);
            si = __builtin_amdgcn_mfma_f32_16x16x32_bf16(nqr0, ki_[kb][0], si, 0,0,0);
            si = __builtin_amdgcn_mfma_f32_16x16x32_bf16(nqr1, ki_[kb][1], si, 0,0,0);
#pragma unroll
            for (int r4 = 0; r4 < 4; ++r4) {
                float s2 = sr[r4]*sr[r4] + si[r4]*si[r4];
                float mg = __builtin_amdgcn_sqrtf(s2);
                float pv = __builtin_amdgcn_exp2f(mg * CEXP);
                l_[r4] += pv;
                psw[(quad*4 + r4)*40 + kb*16 + lc] = (bf16)pv;
            }
        }

        // ---- pre-read next-iteration operands (before barrier, from b0) ----
        pf = *(bf16x8*)&psw[lc*40 + quad*8];
#pragma unroll
        for (int ri = 0; ri < 2; ++ri)
#pragma unroll
            for (int vb = 0; vb < 4; ++vb)
                vf[ri][vb] = *(bf16x8*)&KV[b0 + (2+ri)*2048 + voff[vb]];

        PIPE_SYNC();   // drains tile s+1; tile s+2 stays in flight
        int t = b0; b0 = b1; b1 = b2; b2 = t;
    }

    // ---- final PV (step NSTEP-1) ----
#pragma unroll
    for (int ri = 0; ri < 2; ++ri)
#pragma unroll
        for (int vb = 0; vb < 4; ++vb)
            O[ri][vb] = __builtin_amdgcn_mfma_f32_16x16x32_bf16(
                pf, vf[ri][vb], O[ri][vb], 0, 0, 0);

    // ---- row-sum reduce over 16 lc lanes, normalize, store ----
#pragma unroll
    for (int off = 1; off < 16; off <<= 1)
#pragma unroll
        for (int r = 0; r < 4; ++r)
            l_[r] += __shfl_xor(l_[r], off);
    float inv[4];
#pragma unroll
    for (int r = 0; r < 4; ++r) inv[r] = 1.f / l_[r];

    bf16* obr = obuf + ((size_t)(b)*NN_)*DIM_;
    bf16* obi = obuf + ((size_t)(BB_ + b)*NN_)*DIM_;
#pragma unroll
    for (int vb = 0; vb < 4; ++vb)
#pragma unroll
        for (int r = 0; r < 4; ++r) {
            int gn = q0 + quad*4 + r;
            int gc = h*HD_ + vb*16 + lc;
            obr[(size_t)gn*DIM_ + gc] = (bf16)(O[0][vb][r] * inv[r]);
            obi[(size_t)gn*DIM_ + gc] = (bf16)(O[1][vb][r] * inv[r]);
        }
}

// ---------------------------------------------------------------------------
// Legacy (round-3) GEMMs — fallback when ws_size < 84 MB.
// ---------------------------------------------------------------------------
__global__ __launch_bounds__(256) void qkv_gemm_legacy(
    const float* __restrict__ xr, const float* __restrict__ xi,
    const float* __restrict__ Wr, const float* __restrict__ Wi,
    const float* __restrict__ br, const float* __restrict__ bi,
    bf16* __restrict__ qbuf, bf16* __restrict__ kbuf, bf16* __restrict__ vbuf)
{
    const int z = blockIdx.z;
    const float* __restrict__ A    = z ? xi : xr;
    const float* __restrict__ W    = z ? Wi : Wr;
    const float* __restrict__ bias = z ? bi : br;
    const int n0 = blockIdx.x * 128;
    const int m0 = blockIdx.y * 128;

    __shared__ bf16 As[128*40];
    __shared__ bf16 Bs[128*40];

    const int tid  = threadIdx.x;
    const int w    = tid >> 6, lane = tid & 63;
    const int quad = lane >> 4, lc = lane & 15;
    const int wm   = (w >> 1) * 64, wn = (w & 1) * 64;

    const fx4 fzero = {0.f, 0.f, 0.f, 0.f};
    fx4 acc[4][4];
#pragma unroll
    for (int mi = 0; mi < 4; ++mi)
#pragma unroll
        for (int ni = 0; ni < 4; ++ni) acc[mi][ni] = fzero;

    for (int k0 = 0; k0 < DIM_; k0 += 32) {
#pragma unroll
        for (int it = 0; it < 2; ++it) {
            int flat = it*2048 + tid*8;
            int row = flat >> 5, col = flat & 31;
            const float* pa = A + (size_t)(m0+row)*DIM_ + k0 + col;
            const float* pb = W + (size_t)(n0+row)*DIM_ + k0 + col;
            fx4 a0 = *(const fx4*)pa, a1 = *(const fx4*)(pa+4);
            fx4 b0 = *(const fx4*)pb, b1 = *(const fx4*)(pb+4);
            bf16x8 av, bv;
#pragma unroll
            for (int j = 0; j < 4; ++j) {
                av[j] = (bf16)a0[j]; av[j+4] = (bf16)a1[j];
                bv[j] = (bf16)b0[j]; bv[j+4] = (bf16)b1[j];
            }
            *(bf16x8*)&As[row*40 + col] = av;
            *(bf16x8*)&Bs[row*40 + col] = bv;
        }
        __syncthreads();

        bf16x8 af[4], bfr[4];
#pragma unroll
        for (int mi = 0; mi < 4; ++mi) af[mi]  = *(bf16x8*)&As[(wm + mi*16 + lc)*40 + quad*8];
#pragma unroll
        for (int ni = 0; ni < 4; ++ni) bfr[ni] = *(bf16x8*)&Bs[(wn + ni*16 + lc)*40 + quad*8];
#pragma unroll
        for (int mi = 0; mi < 4; ++mi)
#pragma unroll
            for (int ni = 0; ni < 4; ++ni)
                acc[mi][ni] = __builtin_amdgcn_mfma_f32_16x16x32_bf16(af[mi], bfr[ni], acc[mi][ni], 0, 0, 0);
        __syncthreads();
    }

#pragma unroll
    for (int mi = 0; mi < 4; ++mi)
#pragma unroll
        for (int ni = 0; ni < 4; ++ni)
#pragma unroll
            for (int r = 0; r < 4; ++r) {
                int gm = m0 + wm + mi*16 + quad*4 + r;
                int gc = n0 + wn + ni*16 + lc;
                float val = acc[mi][ni][r] + bias[gc];
                bf16 bv = (bf16)val;
                int which = gc >> 10, h = (gc >> 6) & 15, hd = gc & 63;
                int b = gm >> 11, n = gm & 2047;
                size_t base = (size_t)((z*BB_ + b)*HEADS_ + h);
                if (which == 0)      qbuf[(base*NN_ + n)*HD_ + hd] = bv;
                else if (which == 1) kbuf[(base*NN_ + n)*HD_ + hd] = bv;
                else                 vbuf[(base*HD_ + hd)*NN_ + n] = bv;
            }
}

__global__ __launch_bounds__(256) void out_gemm_legacy(
    const bf16* __restrict__ obuf,
    const float* __restrict__ Wr, const float* __restrict__ Wi,
    const float* __restrict__ br, const float* __restrict__ bi,
    float* __restrict__ out)
{
    const int z = blockIdx.z;
    const bf16*  __restrict__ A    = obuf + (size_t)z * MTOT_ * DIM_;
    const float* __restrict__ W    = z ? Wi : Wr;
    const float* __restrict__ bias = z ? bi : br;
    float* __restrict__ dst        = out + (size_t)z * MTOT_ * DIM_;
    const int n0 = blockIdx.x * 128;
    const int m0 = blockIdx.y * 128;

    __shared__ bf16 As[128*40];
    __shared__ bf16 Bs[128*40];

    const int tid  = threadIdx.x;
    const int w    = tid >> 6, lane = tid & 63;
    const int quad = lane >> 4, lc = lane & 15;
    const int wm   = (w >> 1) * 64, wn = (w & 1) * 64;

    const fx4 fzero = {0.f, 0.f, 0.f, 0.f};
    fx4 acc[4][4];
#pragma unroll
    for (int mi = 0; mi < 4; ++mi)
#pragma unroll
        for (int ni = 0; ni < 4; ++ni) acc[mi][ni] = fzero;

    for (int k0 = 0; k0 < DIM_; k0 += 32) {
#pragma unroll
        for (int it = 0; it < 2; ++it) {
            int flat = it*2048 + tid*8;
            int row = flat >> 5, col = flat & 31;
            *(bf16x8*)&As[row*40 + col] = *(const bf16x8*)(A + (size_t)(m0+row)*DIM_ + k0 + col);
            const float* pb = W + (size_t)(n0+row)*DIM_ + k0 + col;
            fx4 b0 = *(const fx4*)pb, b1 = *(const fx4*)(pb+4);
            bf16x8 bv;
#pragma unroll
            for (int j = 0; j < 4; ++j) { bv[j] = (bf16)b0[j]; bv[j+4] = (bf16)b1[j]; }
            *(bf16x8*)&Bs[row*40 + col] = bv;
        }
        __syncthreads();

        bf16x8 af[4], bfr[4];
#pragma unroll
        for (int mi = 0; mi < 4; ++mi) af[mi]  = *(bf16x8*)&As[(wm + mi*16 + lc)*40 + quad*8];
#pragma unroll
        for (int ni = 0; ni < 4; ++ni) bfr[ni] = *(bf16x8*)&Bs[(wn + ni*16 + lc)*40 + quad*8];
#pragma unroll
        for (int mi = 0; mi < 4; ++mi)
#pragma unroll
            for (int ni = 0; ni < 4; ++ni)
                acc[mi][ni] = __builtin_amdgcn_mfma_f32_16x16x32_bf16(af[mi], bfr[ni], acc[mi][ni], 0, 0, 0);
        __syncthreads();
    }

#pragma unroll
    for (int mi = 0; mi < 4; ++mi)
#pragma unroll
        for (int ni = 0; ni < 4; ++ni)
#pragma unroll
            for (int r = 0; r < 4; ++r) {
                int gm = m0 + wm + mi*16 + quad*4 + r;
                int gc = n0 + wn + ni*16 + lc;
                dst[(size_t)gm*DIM_ + gc] = acc[mi][ni][r] + bias[gc];
            }
}

// ---------------------------------------------------------------------------
extern "C" void kernel_launch(void* const* d_in, const int* in_sizes, int n_in,
                              void* d_out, int out_size, void* d_ws, size_t ws_size,
                              hipStream_t stream) {
    const float* xr  = (const float*)d_in[0];
    const float* xi  = (const float*)d_in[1];
    const float* Wqr = (const float*)d_in[2];
    const float* bqr = (const float*)d_in[3];
    const float* Wqi = (const float*)d_in[4];
    const float* bqi = (const float*)d_in[5];
    const float* Wor = (const float*)d_in[6];
    const float* bor = (const float*)d_in[7];
    const float* Woi = (const float*)d_in[8];
    const float* boi = (const float*)d_in[9];
    float* out = (float*)d_out;

    bf16* ws = (bf16*)d_ws;
    const size_t NEED = 83886080ull;

    if (ws_size >= NEED) {
        bf16* xbf  = ws;               // reused as obuf after qkv
        bf16* wqkv = ws + 8388608;
        bf16* wout = ws + 14680064;
        bf16* qb   = ws + 16777216;
        bf16* kb   = ws + 25165824;
        bf16* vb   = ws + 33554432;
        bf16* obuf = xbf;

        cvt_prepass<<<dim3(8192), 256, 0, stream>>>(xr, xi, Wqr, Wqi, Wor, Woi,
                                                    xbf, wqkv, wout);
        qkv_gemm_dma<<<dim3(24, 32, 2), 256, 0, stream>>>(xbf, wqkv, bqr, bqi,
                                                          qb, kb, vb);
        attn_fwd<<<dim3(512), 512, 0, stream>>>(qb, kb, vb, obuf);
        out_gemm_dma<<<dim3(8, 32, 2), 256, 0, stream>>>(obuf, wout, bor, boi, out);
    } else {
        const size_t per = (size_t)2 * BB_ * HEADS_ * NN_ * HD_;
        bf16* qb   = ws;
        bf16* kb   = ws + per;
        bf16* vb   = ws + 2*per;
        bf16* obuf = ws + 3*per;
        qkv_gemm_legacy<<<dim3(24, 32, 2), 256, 0, stream>>>(xr, xi, Wqr, Wqi,
                                                             bqr, bqi, qb, kb, vb);
        attn_fwd<<<dim3(512), 512, 0, stream>>>(qb, kb, vb, obuf);
        out_gemm_legacy<<<dim3(8, 32, 2), 256, 0, stream>>>(obuf, Wor, Woi,
                                                            bor, boi, out);
    }
}